// Round 7
// baseline (156.791 us; speedup 1.0000x reference)
//
#include <hip/hip_runtime.h>
#include <hip/hip_bf16.h>

// RGCN CSR, two layers, MI355X.  Transform-then-gather.
//   xw1[(n*8+r)*64 + f] = (x @ W1[r])[n,f]   (dense GEMM, K=64, bf16 MFMA, f32 A fused-cast)
//   h[n,f] = relu( sum_{e in row n} xw1[(idx_e*8+rel_e)*64 + f] )
//   xw2[(n*8+r)*40 + f] = (h @ W2[r])[n,f]
//   out = log_softmax( sum_e xw2[...] )
// R7: k_xw occupancy fix — 16 rows/wave and the col-slab range split 2-way
// across blocks: grid 586 -> 2344 blocks (9376 waves > 8192 slots; R6 ran at
// 16% occupancy, latency-bound at 2.2 TB/s). A fetched twice (2nd pass L3-hot).
// Gather byte-offsets in 32-bit (buffers < 4GB) to drop 64-bit add chains.

typedef __attribute__((ext_vector_type(8))) short short8;
typedef __attribute__((ext_vector_type(4))) float floatx4;

static __device__ __forceinline__ unsigned short f2bf(float f) {
    unsigned u = __float_as_uint(f);
    u += 0x7FFFu + ((u >> 16) & 1u);      // RNE
    return (unsigned short)(u >> 16);
}
static __device__ __forceinline__ float bflo(unsigned u) { return __uint_as_float(u << 16); }
static __device__ __forceinline__ float bfhi(unsigned u) { return __uint_as_float(u & 0xffff0000u); }

// ---- pack weights as B^T with K = input-feature dim ----
// BT1[j][d] = W1[r][d][f], j = r*64+f   (512 x 64)
// BT2[j][d] = W2[r][d][f], j = r*40+f   (320 x 64)
__global__ void k_packw(const float* __restrict__ W1, const float* __restrict__ W2,
                        unsigned short* __restrict__ BT1, unsigned short* __restrict__ BT2) {
    int i = blockIdx.x * 256 + threadIdx.x;
    if (i < 512 * 64) {
        int j = i >> 6, d = i & 63;
        int r = j >> 6, f = j & 63;
        BT1[i] = f2bf(W1[r * 4096 + d * 64 + f]);
    } else if (i < 512 * 64 + 320 * 64) {
        int ii = i - 512 * 64;
        int j = ii >> 6, d = ii & 63;
        int r = j / 40, f = j - r * 40;
        BT2[ii] = f2bf(W2[r * 2560 + d * 40 + f]);
    }
}

// ---- dense GEMM: xw[MP][NC] = A[MP][64] @ BT[NC][64]^T  (K=64, bf16 MFMA) ----
// AF32=1: A is f32 (x), rows >= M read as zero (fused cast). AF32=0: A bf16 (h).
// Wave owns 16 rows; A-frags in registers (read once per block-half); each
// block handles half the col-slabs (bid&1) for 2x grid parallelism.
template <int AF32>
__global__ __launch_bounds__(256) void k_xw(
    const void* __restrict__ Av, const unsigned short* __restrict__ BT,
    unsigned short* __restrict__ xw, int NC, int nColBlk, int M) {
    int bid = blockIdx.x;
    int half = bid & 1, rb = bid >> 1;
    int h0 = (nColBlk + 1) >> 1;
    int cb0 = half ? h0 : 0;
    int cb1 = half ? nColBlk : h0;
    int wave = threadIdx.x >> 6, lane = threadIdx.x & 63;
    int lr = lane & 15, lg = lane >> 4;
    int rowbase = (rb * 4 + wave) * 16;

    short8 af[2];                             // [k0] — A read once per half
#pragma unroll
    for (int k0 = 0; k0 < 2; ++k0) {
        int row = rowbase + lr;
        int koff = k0 * 32 + lg * 8;
        if constexpr (AF32) {
            const float* Af = (const float*)Av;
            float4 v0 = {0, 0, 0, 0}, v1 = {0, 0, 0, 0};
            if (row < M) {
                v0 = *(const float4*)(Af + (size_t)row * 64 + koff);
                v1 = *(const float4*)(Af + (size_t)row * 64 + koff + 4);
            }
            short8 t;
            t[0] = (short)f2bf(v0.x); t[1] = (short)f2bf(v0.y);
            t[2] = (short)f2bf(v0.z); t[3] = (short)f2bf(v0.w);
            t[4] = (short)f2bf(v1.x); t[5] = (short)f2bf(v1.y);
            t[6] = (short)f2bf(v1.z); t[7] = (short)f2bf(v1.w);
            af[k0] = t;
        } else {
            const unsigned short* Ab = (const unsigned short*)Av;
            af[k0] = *(const short8*)(Ab + (size_t)row * 64 + koff);
        }
    }

    for (int cb = cb0; cb < cb1; ++cb) {
        int col0 = cb * 64;
        floatx4 acc[4] = {};
#pragma unroll
        for (int k0 = 0; k0 < 2; ++k0) {
            int koff = k0 * 32 + lg * 8;
            short8 b[4];
#pragma unroll
            for (int nt = 0; nt < 4; ++nt)
                b[nt] = *(const short8*)(BT + (size_t)(col0 + nt * 16 + lr) * 64 + koff);
#pragma unroll
            for (int nt = 0; nt < 4; ++nt)
                acc[nt] = __builtin_amdgcn_mfma_f32_16x16x32_bf16(af[k0], b[nt], acc[nt], 0, 0, 0);
        }
        // C/D layout: col = lane&15, row = (lane>>4)*4 + i
#pragma unroll
        for (int nt = 0; nt < 4; ++nt)
#pragma unroll
            for (int i = 0; i < 4; ++i) {
                int row = rowbase + lg * 4 + i;             // always < MP
                xw[(size_t)row * NC + col0 + nt * 16 + lr] = f2bf(acc[nt][i]);
            }
    }
}

// ---- gather-sum + relu -> h bf16 [MP][64]; zero pad rows ----
// 2 rows per wave: half-wave eo owns one row; lane loads dword (2 bf16) at
// feature pair fl. 16 dword loads in flight cover 32 cache lines.
__global__ __launch_bounds__(256) void k_gs_relu(
    const unsigned short* __restrict__ xw,   // viewed as [(n*8+r)][64]
    const int* __restrict__ ptr, const int* __restrict__ idx,
    const int* __restrict__ rel,
    unsigned short* __restrict__ H, int M, int MP) {
    int rowA = (blockIdx.x * 4 + (threadIdx.x >> 6)) * 2;
    if (rowA >= MP) return;
    rowA = __builtin_amdgcn_readfirstlane(rowA);
    int lane = threadIdx.x & 63;
    int fl = lane & 31, eo = lane >> 5;
    int rowB = rowA + 1;
    int myrow = eo ? rowB : rowA;
    if (rowA >= M) {                          // pad pair -> zeros
        *(unsigned*)(H + (size_t)myrow * 64 + fl * 2) = 0;
        return;
    }
    float cx = 0.f, cy = 0.f;
    bool both = (rowB < M);
    int p0 = ptr[rowA], p1 = ptr[rowA + 1];
    int p2 = both ? ptr[rowA + 2] : p1;
    if (both && (p1 - p0 == 16) && (p2 - p1 == 16)) {
        const int* ia = idx + p0; const int* ra_ = rel + p0;   // scalar (uniform)
        const int* ib = idx + p1; const int* rb_ = rel + p1;
        unsigned u[16];
#pragma unroll
        for (int t = 0; t < 16; ++t) {
            unsigned bA = ((unsigned)ia[t] * 8u + (unsigned)ra_[t]) * 128u;  // 32-bit offsets
            unsigned bB = ((unsigned)ib[t] * 8u + (unsigned)rb_[t]) * 128u;
            unsigned b = eo ? bB : bA;
            u[t] = *(const unsigned*)((const char*)xw + b + fl * 4);
        }
#pragma unroll
        for (int t = 0; t < 16; ++t) { cx += bflo(u[t]); cy += bfhi(u[t]); }
    } else {
        int ps = 0, deg = 0;
        if (myrow < M) { ps = ptr[myrow]; deg = ptr[myrow + 1] - ps; }
        for (int t = 0; t < deg; ++t) {
            unsigned b = ((unsigned)idx[ps + t] * 8u + (unsigned)rel[ps + t]) * 128u;
            unsigned u = *(const unsigned*)((const char*)xw + b + fl * 4);
            cx += bflo(u); cy += bfhi(u);
        }
    }
    unsigned o = ((unsigned)f2bf(fmaxf(cy, 0.f)) << 16) | f2bf(fmaxf(cx, 0.f));
    *(unsigned*)(H + (size_t)myrow * 64 + fl * 2) = o;
}

// ---- gather-sum + log_softmax -> out f32 [M][40] ----
// Same 2-rows/wave structure; row stride is 40 bf16 (80B); lanes fl<20 valid.
__global__ __launch_bounds__(256) void k_gs_lsm(
    const unsigned short* __restrict__ xw,   // viewed as [(n*8+r)][40]
    const int* __restrict__ ptr, const int* __restrict__ idx,
    const int* __restrict__ rel,
    float* __restrict__ out, int M) {
    int rowA = (blockIdx.x * 4 + (threadIdx.x >> 6)) * 2;
    if (rowA >= M) return;
    rowA = __builtin_amdgcn_readfirstlane(rowA);
    int lane = threadIdx.x & 63;
    int fl = lane & 31, eo = lane >> 5;
    int rowB = rowA + 1;
    int myrow = eo ? rowB : rowA;
    bool okf = fl < 20;
    int flc = okf ? fl : 0;
    float cx = 0.f, cy = 0.f;
    bool both = (rowB < M);
    int p0 = ptr[rowA], p1 = ptr[rowA + 1];
    int p2 = both ? ptr[rowA + 2] : p1;
    if (both && (p1 - p0 == 16) && (p2 - p1 == 16)) {
        const int* ia = idx + p0; const int* ra_ = rel + p0;
        const int* ib = idx + p1; const int* rb_ = rel + p1;
        unsigned u[16];
#pragma unroll
        for (int t = 0; t < 16; ++t) {
            unsigned bA = ((unsigned)ia[t] * 8u + (unsigned)ra_[t]) * 80u;
            unsigned bB = ((unsigned)ib[t] * 8u + (unsigned)rb_[t]) * 80u;
            unsigned b = eo ? bB : bA;
            u[t] = *(const unsigned*)((const char*)xw + b + flc * 4);
        }
#pragma unroll
        for (int t = 0; t < 16; ++t) { cx += bflo(u[t]); cy += bfhi(u[t]); }
    } else {
        int ps = 0, deg = 0;
        if (myrow < M) { ps = ptr[myrow]; deg = ptr[myrow + 1] - ps; }
        for (int t = 0; t < deg; ++t) {
            unsigned b = ((unsigned)idx[ps + t] * 8u + (unsigned)rel[ps + t]) * 80u;
            unsigned u = *(const unsigned*)((const char*)xw + b + flc * 4);
            cx += bflo(u); cy += bfhi(u);
        }
    }
    // log-softmax over this half-wave's 40 values (lanes fl<20 hold 2 each)
    float mx = okf ? fmaxf(cx, cy) : -INFINITY;
#pragma unroll
    for (int m = 1; m < 32; m <<= 1) mx = fmaxf(mx, __shfl_xor(mx, m, 32));
    float s = okf ? (__expf(cx - mx) + __expf(cy - mx)) : 0.f;
#pragma unroll
    for (int m = 1; m < 32; m <<= 1) s += __shfl_xor(s, m, 32);
    float lse = mx + __logf(s);
    if (okf && myrow < M) {
        float2 o = {cx - lse, cy - lse};
        *(float2*)(out + (size_t)myrow * 40 + flc * 2) = o;
    }
}

extern "C" void kernel_launch(void* const* d_in, const int* in_sizes, int n_in,
                              void* d_out, int out_size, void* d_ws, size_t ws_size,
                              hipStream_t stream) {
    const float* x  = (const float*)d_in[0];
    const int* ptr  = (const int*)d_in[1];
    const int* idx  = (const int*)d_in[2];
    const int* rel  = (const int*)d_in[3];
    const float* W1 = (const float*)d_in[4];
    const float* W2 = (const float*)d_in[5];
    float* out = (float*)d_out;

    int N = in_sizes[1] - 1;                 // 75000
    int MP = (N + 255) & ~255;               // 75008 (multiple of 256)

    char* ws = (char*)d_ws;
    size_t szRow64 = (size_t)MP * 64 * 2;    // 9.6MB
    unsigned short* hbf = (unsigned short*)ws;
    unsigned short* BT1 = (unsigned short*)(ws + szRow64);
    unsigned short* BT2 = BT1 + 512 * 64;
    unsigned short* xwb = BT2 + 320 * 64;
    // xw1 [MP][512] = 76.8MB; xw2 [MP][320] aliases it.  Total ws ~= 86.5MB.

    k_packw<<<(512 * 64 + 320 * 64 + 255) / 256, 256, 0, stream>>>(W1, W2, BT1, BT2);

    int nblk = (MP / 64) * 2;                // 2344 blocks: 4 waves x 16 rows, 2 col-halves
    // layer 1: xw1 = cast(x) @ W1 (NC=512, slabs 0..3 / 4..7 per block-half)
    k_xw<1><<<nblk, 256, 0, stream>>>((const void*)x, BT1, xwb, 512, 8, N);
    k_gs_relu<<<MP / 8, 256, 0, stream>>>(xwb, ptr, idx, rel, hbf, N, MP);
    // layer 2: xw2 = h @ W2 (NC=320, slabs 0..2 / 3..4), aliases xwb
    k_xw<0><<<nblk, 256, 0, stream>>>((const void*)hbf, BT2, xwb, 320, 5, MP);
    k_gs_lsm<<<(N + 7) / 8, 256, 0, stream>>>(xwb, ptr, idx, rel, out, N);
}

// Round 8
// 149.380 us; speedup vs baseline: 1.0496x; 1.0496x over previous
//
#include <hip/hip_runtime.h>
#include <hip/hip_bf16.h>

// RGCN CSR, two layers, MI355X.  Transform-then-gather.
//   xw1[n][512] = x @ W1flat   (K=64 bf16 MFMA, fused f32->bf16 cast of A)
//   h[n][64]    = relu(sum_{e in row n} xw1[idx_e][slab rel_e])
//   xw2[n][320] = h @ W2flat
//   out[n][40]  = log_softmax(sum_e xw2[idx_e][rel_e*40..+40])
// R8: k_xw epilogue rebuilt. R6/R7 showed both GEMMs pinned at ~55us with
// nothing busy -> 2B scalar store stream (partial-line, vmcnt-polluting) was
// the bottleneck. Operand-swapped MFMA (mfma(b,a,acc)) gives each thread 4
// CONSECUTIVE cols of one row; sigma col-interleave (within-slab involution
// g*16+l*4+i <-> l*16+g*4+i) makes the thread's 16 values contiguous ->
// 2x16B stores/slab (was 32x2B), full 64B lines per wave-inst. Gathers are
// slab-elementwise so layer-1 permutation is transparent; BT2 k-dim gets
// sigma in packw; layer-2 output stays logical (8B stores).

typedef __attribute__((ext_vector_type(8))) short short8;
typedef __attribute__((ext_vector_type(4))) float floatx4;

static __device__ __forceinline__ unsigned short f2bf(float f) {
    unsigned u = __float_as_uint(f);
    u += 0x7FFFu + ((u >> 16) & 1u);      // RNE
    return (unsigned short)(u >> 16);
}
static __device__ __forceinline__ float bflo(unsigned u) { return __uint_as_float(u << 16); }
static __device__ __forceinline__ float bfhi(unsigned u) { return __uint_as_float(u & 0xffff0000u); }

// sigma: within-slab col interleave, involution on [0,64)
static __device__ __forceinline__ int sgm(int d) {
    return ((d & 12) << 2) | ((d & 48) >> 2) | (d & 3);
}

// ---- pack weights as B^T with K = input-feature dim ----
// BT1[j][d] = W1[r][d][f], j = r*64+f          (512 x 64)   [logical rows]
// BT2[j][d] = W2[r][sgm(d)][f], j = r*40+f     (320 x 64)   [k-dim in h's phys order]
__global__ void k_packw(const float* __restrict__ W1, const float* __restrict__ W2,
                        unsigned short* __restrict__ BT1, unsigned short* __restrict__ BT2) {
    int i = blockIdx.x * 256 + threadIdx.x;
    if (i < 512 * 64) {
        int j = i >> 6, d = i & 63;
        int r = j >> 6, f = j & 63;
        BT1[i] = f2bf(W1[r * 4096 + d * 64 + f]);
    } else if (i < 512 * 64 + 320 * 64) {
        int ii = i - 512 * 64;
        int j = ii >> 6, d = ii & 63;
        int r = j / 40, f = j - r * 40;
        BT2[ii] = f2bf(W2[r * 2560 + sgm(d) * 40 + f]);
    }
}

// ---- dense GEMM: xw[MP][NC] = A[MP][64] @ BT[NC][64]^T  (K=64, bf16 MFMA) ----
// AF32=1: A f32 (x), rows>=M read 0 (fused cast), sigma-phys output, 16B stores.
// AF32=0: A bf16 (h, phys layout), logical output, 8B stores.
// Wave owns 16 rows x all NC cols; A-frags in regs (read once); operand-swapped
// MFMA: acc[g] holds 4 consecutive logical cols of row (lane&15).
template <int AF32>
__global__ __launch_bounds__(256) void k_xw(
    const void* __restrict__ Av, const unsigned short* __restrict__ BT,
    unsigned short* __restrict__ xw, int NC, int nColBlk, int M) {
    int wave = threadIdx.x >> 6, lane = threadIdx.x & 63;
    int lr = lane & 15, lg = lane >> 4;
    int rowbase = (blockIdx.x * 4 + wave) * 16;
    int row = rowbase + lr;

    short8 af[2];                             // [k0] — A read exactly once
#pragma unroll
    for (int k0 = 0; k0 < 2; ++k0) {
        int koff = k0 * 32 + lg * 8;
        if constexpr (AF32) {
            const float* Af = (const float*)Av;
            float4 v0 = {0, 0, 0, 0}, v1 = {0, 0, 0, 0};
            if (row < M) {
                v0 = *(const float4*)(Af + (size_t)row * 64 + koff);
                v1 = *(const float4*)(Af + (size_t)row * 64 + koff + 4);
            }
            short8 t;
            t[0] = (short)f2bf(v0.x); t[1] = (short)f2bf(v0.y);
            t[2] = (short)f2bf(v0.z); t[3] = (short)f2bf(v0.w);
            t[4] = (short)f2bf(v1.x); t[5] = (short)f2bf(v1.y);
            t[6] = (short)f2bf(v1.z); t[7] = (short)f2bf(v1.w);
            af[k0] = t;
        } else {
            const unsigned short* Ab = (const unsigned short*)Av;
            af[k0] = *(const short8*)(Ab + (size_t)row * 64 + koff);
        }
    }

    for (int cb = 0; cb < nColBlk; ++cb) {
        int col0 = cb * 64;
        floatx4 acc[4] = {};
#pragma unroll
        for (int k0 = 0; k0 < 2; ++k0) {
            int koff = k0 * 32 + lg * 8;
            short8 b[4];
#pragma unroll
            for (int g = 0; g < 4; ++g)
                b[g] = *(const short8*)(BT + (size_t)(col0 + g * 16 + lr) * 64 + koff);
            // operand swap: BT rows are the M-side, A rows the N-side.
#pragma unroll
            for (int g = 0; g < 4; ++g)
                acc[g] = __builtin_amdgcn_mfma_f32_16x16x32_bf16(b[g], af[k0], acc[g], 0, 0, 0);
        }
        // thread holds: row = rowbase+lr; logical cols col0 + g*16 + lg*4 + i
        if constexpr (AF32) {
            // sigma-phys store: phys within-slab = lg*16 + g*4 + i -> 16 contiguous
            short8 o0, o1;
#pragma unroll
            for (int g = 0; g < 2; ++g)
#pragma unroll
                for (int i = 0; i < 4; ++i) {
                    o0[g * 4 + i] = (short)f2bf(acc[g][i]);
                    o1[g * 4 + i] = (short)f2bf(acc[g + 2][i]);
                }
            unsigned short* p = xw + (size_t)row * NC + col0 + lg * 16;
            *(short8*)p = o0;
            *(short8*)(p + 8) = o1;
        } else {
            // logical store: 4 cols per g -> 8B each
#pragma unroll
            for (int g = 0; g < 4; ++g) {
                unsigned lo = ((unsigned)f2bf(acc[g][1]) << 16) | f2bf(acc[g][0]);
                unsigned hi = ((unsigned)f2bf(acc[g][3]) << 16) | f2bf(acc[g][2]);
                uint2 o = {lo, hi};
                *(uint2*)(xw + (size_t)row * NC + col0 + g * 16 + lg * 4) = o;
            }
        }
    }
}

// ---- gather-sum + relu -> h bf16 [MP][64] (phys layout); zero pad rows ----
// 2 rows per wave: half-wave eo owns one row; lane loads dword (2 bf16).
__global__ __launch_bounds__(256) void k_gs_relu(
    const unsigned short* __restrict__ xw,   // [(n*8+r)][64] phys
    const int* __restrict__ ptr, const int* __restrict__ idx,
    const int* __restrict__ rel,
    unsigned short* __restrict__ H, int M, int MP) {
    int rowA = (blockIdx.x * 4 + (threadIdx.x >> 6)) * 2;
    if (rowA >= MP) return;
    rowA = __builtin_amdgcn_readfirstlane(rowA);
    int lane = threadIdx.x & 63;
    int fl = lane & 31, eo = lane >> 5;
    int rowB = rowA + 1;
    int myrow = eo ? rowB : rowA;
    if (rowA >= M) {                          // pad pair -> zeros
        *(unsigned*)(H + (size_t)myrow * 64 + fl * 2) = 0;
        return;
    }
    float cx = 0.f, cy = 0.f;
    bool both = (rowB < M);
    int p0 = ptr[rowA], p1 = ptr[rowA + 1];
    int p2 = both ? ptr[rowA + 2] : p1;
    if (both && (p1 - p0 == 16) && (p2 - p1 == 16)) {
        const int* ia = idx + p0; const int* ra_ = rel + p0;   // scalar (uniform)
        const int* ib = idx + p1; const int* rb_ = rel + p1;
        unsigned u[16];
#pragma unroll
        for (int t = 0; t < 16; ++t) {
            unsigned bA = ((unsigned)ia[t] * 8u + (unsigned)ra_[t]) * 128u;
            unsigned bB = ((unsigned)ib[t] * 8u + (unsigned)rb_[t]) * 128u;
            unsigned b = eo ? bB : bA;
            u[t] = *(const unsigned*)((const char*)xw + b + fl * 4);
        }
#pragma unroll
        for (int t = 0; t < 16; ++t) { cx += bflo(u[t]); cy += bfhi(u[t]); }
    } else {
        int ps = 0, deg = 0;
        if (myrow < M) { ps = ptr[myrow]; deg = ptr[myrow + 1] - ps; }
        for (int t = 0; t < deg; ++t) {
            unsigned b = ((unsigned)idx[ps + t] * 8u + (unsigned)rel[ps + t]) * 128u;
            unsigned u = *(const unsigned*)((const char*)xw + b + fl * 4);
            cx += bflo(u); cy += bfhi(u);
        }
    }
    unsigned o = ((unsigned)f2bf(fmaxf(cy, 0.f)) << 16) | f2bf(fmaxf(cx, 0.f));
    *(unsigned*)(H + (size_t)myrow * 64 + fl * 2) = o;
}

// ---- gather-sum + log_softmax -> out f32 [M][40]  (xw2 logical layout) ----
__global__ __launch_bounds__(256) void k_gs_lsm(
    const unsigned short* __restrict__ xw,   // [(n*8+r)][40] logical
    const int* __restrict__ ptr, const int* __restrict__ idx,
    const int* __restrict__ rel,
    float* __restrict__ out, int M) {
    int rowA = (blockIdx.x * 4 + (threadIdx.x >> 6)) * 2;
    if (rowA >= M) return;
    rowA = __builtin_amdgcn_readfirstlane(rowA);
    int lane = threadIdx.x & 63;
    int fl = lane & 31, eo = lane >> 5;
    int rowB = rowA + 1;
    int myrow = eo ? rowB : rowA;
    bool okf = fl < 20;
    int flc = okf ? fl : 0;
    float cx = 0.f, cy = 0.f;
    bool both = (rowB < M);
    int p0 = ptr[rowA], p1 = ptr[rowA + 1];
    int p2 = both ? ptr[rowA + 2] : p1;
    if (both && (p1 - p0 == 16) && (p2 - p1 == 16)) {
        const int* ia = idx + p0; const int* ra_ = rel + p0;
        const int* ib = idx + p1; const int* rb_ = rel + p1;
        unsigned u[16];
#pragma unroll
        for (int t = 0; t < 16; ++t) {
            unsigned bA = ((unsigned)ia[t] * 8u + (unsigned)ra_[t]) * 80u;
            unsigned bB = ((unsigned)ib[t] * 8u + (unsigned)rb_[t]) * 80u;
            unsigned b = eo ? bB : bA;
            u[t] = *(const unsigned*)((const char*)xw + b + flc * 4);
        }
#pragma unroll
        for (int t = 0; t < 16; ++t) { cx += bflo(u[t]); cy += bfhi(u[t]); }
    } else {
        int ps = 0, deg = 0;
        if (myrow < M) { ps = ptr[myrow]; deg = ptr[myrow + 1] - ps; }
        for (int t = 0; t < deg; ++t) {
            unsigned b = ((unsigned)idx[ps + t] * 8u + (unsigned)rel[ps + t]) * 80u;
            unsigned u = *(const unsigned*)((const char*)xw + b + flc * 4);
            cx += bflo(u); cy += bfhi(u);
        }
    }
    float mx = okf ? fmaxf(cx, cy) : -INFINITY;
#pragma unroll
    for (int m = 1; m < 32; m <<= 1) mx = fmaxf(mx, __shfl_xor(mx, m, 32));
    float s = okf ? (__expf(cx - mx) + __expf(cy - mx)) : 0.f;
#pragma unroll
    for (int m = 1; m < 32; m <<= 1) s += __shfl_xor(s, m, 32);
    float lse = mx + __logf(s);
    if (okf && myrow < M) {
        float2 o = {cx - lse, cy - lse};
        *(float2*)(out + (size_t)myrow * 40 + flc * 2) = o;
    }
}

extern "C" void kernel_launch(void* const* d_in, const int* in_sizes, int n_in,
                              void* d_out, int out_size, void* d_ws, size_t ws_size,
                              hipStream_t stream) {
    const float* x  = (const float*)d_in[0];
    const int* ptr  = (const int*)d_in[1];
    const int* idx  = (const int*)d_in[2];
    const int* rel  = (const int*)d_in[3];
    const float* W1 = (const float*)d_in[4];
    const float* W2 = (const float*)d_in[5];
    float* out = (float*)d_out;

    int N = in_sizes[1] - 1;                 // 75000
    int MP = (N + 255) & ~255;               // 75008

    char* ws = (char*)d_ws;
    size_t szRow64 = (size_t)MP * 64 * 2;    // 9.6MB
    unsigned short* hbf = (unsigned short*)ws;
    unsigned short* BT1 = (unsigned short*)(ws + szRow64);
    unsigned short* BT2 = BT1 + 512 * 64;
    unsigned short* xwb = BT2 + 320 * 64;
    // xw1 [MP][512] = 76.8MB; xw2 [MP][320] aliases it.  Total ws ~= 86.5MB.

    k_packw<<<(512 * 64 + 320 * 64 + 255) / 256, 256, 0, stream>>>(W1, W2, BT1, BT2);

    int nblk = MP / 64;                      // 1172 blocks: 4 waves x 16 rows, all slabs
    // layer 1: xw1 = cast(x) @ W1 (NC=512, 8 slabs, sigma-phys cols)
    k_xw<1><<<nblk, 256, 0, stream>>>((const void*)x, BT1, xwb, 512, 8, N);
    k_gs_relu<<<MP / 8, 256, 0, stream>>>(xwb, ptr, idx, rel, hbf, N, MP);
    // layer 2: xw2 = h @ W2 (NC=320, 5 slabs, logical cols), aliases xwb
    k_xw<0><<<nblk, 256, 0, stream>>>((const void*)hbf, BT2, xwb, 320, 5, MP);
    k_gs_lsm<<<(N + 7) / 8, 256, 0, stream>>>(xwb, ptr, idx, rel, out, N);
}

// Round 9
// 110.784 us; speedup vs baseline: 1.4153x; 1.3484x over previous
//
#include <hip/hip_runtime.h>
#include <hip/hip_bf16.h>

// RGCN CSR, two layers, MI355X.  Transform-then-gather.
//   xw1[n][512] = x @ W1flat   (K=64 bf16 MFMA, fused f32->bf16 cast of A)
//   h[n][64]    = relu(sum_{e in row n} xw1[idx_e][slab rel_e])
//   xw2[n][320] = h @ W2flat
//   out[n][40]  = log_softmax(sum_e xw2[idx_e][rel_e*40..+40])
// R9: B operand moved to LDS. R8 still pinned at ~50us with nothing busy:
// every wave re-read the whole 64KB BT from L2 (~300-600MB of L2 traffic on a
// 64KB hot spot) AND the per-slab s_waitcnt on B-loads drained the previous
// slab's HBM stores (shared vmcnt queue). Fix: packw emits BT in
// fragment-linear order (1KB chunk per (slab,k0,g), lane's 16B at lane*16);
// each block stages it to LDS once (+1 barrier); slab loop reads B via
// linear conflict-free ds_read_b128 (lgkmcnt only -> stores fire-and-forget).

typedef __attribute__((ext_vector_type(8))) short short8;
typedef __attribute__((ext_vector_type(4))) float floatx4;

static __device__ __forceinline__ unsigned short f2bf(float f) {
    unsigned u = __float_as_uint(f);
    u += 0x7FFFu + ((u >> 16) & 1u);      // RNE
    return (unsigned short)(u >> 16);
}
static __device__ __forceinline__ float bflo(unsigned u) { return __uint_as_float(u << 16); }
static __device__ __forceinline__ float bfhi(unsigned u) { return __uint_as_float(u & 0xffff0000u); }

// sigma: within-slab col interleave, involution on [0,64)
static __device__ __forceinline__ int sgm(int d) {
    return ((d & 12) << 2) | ((d & 48) >> 2) | (d & 3);
}

// ---- pack weights into fragment-linear BTf ----
// chunk = (cb*2+k0)*4+g (1KB each); within chunk, lane=lg*16+lr holds 8 shorts:
//   BTf[chunk*512 + lg*128 + lr*8 + s] = B[cb*64+g*16+lr][k0*32+lg*8+s]
// Layer1: B[j][d] = W1[r][d][f], j=r*64+f.       (8 slabs, 32768 shorts)
// Layer2: B[j][d] = W2[r][sgm(d)][f], j=r*40+f.  (5 slabs, 20480 shorts; h is sigma-phys)
__global__ void k_packw(const float* __restrict__ W1, const float* __restrict__ W2,
                        unsigned short* __restrict__ BTf1, unsigned short* __restrict__ BTf2) {
    int i = blockIdx.x * 256 + threadIdx.x;
    if (i < 32768) {
        int chunk = i >> 9, w = i & 511;
        int cb = chunk >> 3, k0 = (chunk >> 2) & 1, g = chunk & 3;
        int lg = w >> 7, lr = (w >> 3) & 15, s = w & 7;
        int j = cb * 64 + g * 16 + lr;
        int d = k0 * 32 + lg * 8 + s;
        int r = j >> 6, f = j & 63;
        BTf1[i] = f2bf(W1[r * 4096 + d * 64 + f]);
    } else if (i < 32768 + 20480) {
        int ii = i - 32768;
        int chunk = ii >> 9, w = ii & 511;
        int cb = chunk >> 3, k0 = (chunk >> 2) & 1, g = chunk & 3;
        int lg = w >> 7, lr = (w >> 3) & 15, s = w & 7;
        int j = cb * 64 + g * 16 + lr;                 // < 320
        int d = k0 * 32 + lg * 8 + s;
        int r = j / 40, f = j - r * 40;
        BTf2[ii] = f2bf(W2[r * 2560 + sgm(d) * 40 + f]);
    }
}

// ---- dense GEMM: xw[MP][NC] = A[MP][64] @ B^T  (K=64, bf16 MFMA, B in LDS) ----
// AF32=1: A f32 (x), rows>=M read 0 (fused cast), sigma-phys output, 2x16B stores.
// AF32=0: A bf16 (h phys), logical output, 8B stores.
// Wave owns 16 rows; operand-swapped MFMA: acc[g] = 4 consecutive cols of one row.
template <int AF32, int NSLAB>
__global__ __launch_bounds__(256) void k_xw(
    const void* __restrict__ Av, const unsigned short* __restrict__ BTf,
    unsigned short* __restrict__ xw, int M) {
    constexpr int NC = NSLAB * 64;
    __shared__ short Bs[NSLAB * 4096];       // NSLAB*8KB

    // stage BTf -> LDS (coalesced, once per block)
#pragma unroll
    for (int off = 0; off < NSLAB * 4096; off += 2048)
        *(short8*)(Bs + off + threadIdx.x * 8) =
            *(const short8*)((const short*)BTf + off + threadIdx.x * 8);

    int wave = threadIdx.x >> 6, lane = threadIdx.x & 63;
    int lr = lane & 15, lg = lane >> 4;
    int rowbase = (blockIdx.x * 4 + wave) * 16;
    int row = rowbase + lr;

    short8 af[2];                             // [k0] — A read exactly once
#pragma unroll
    for (int k0 = 0; k0 < 2; ++k0) {
        int koff = k0 * 32 + lg * 8;
        if constexpr (AF32) {
            const float* Af = (const float*)Av;
            float4 v0 = {0, 0, 0, 0}, v1 = {0, 0, 0, 0};
            if (row < M) {
                v0 = *(const float4*)(Af + (size_t)row * 64 + koff);
                v1 = *(const float4*)(Af + (size_t)row * 64 + koff + 4);
            }
            short8 t;
            t[0] = (short)f2bf(v0.x); t[1] = (short)f2bf(v0.y);
            t[2] = (short)f2bf(v0.z); t[3] = (short)f2bf(v0.w);
            t[4] = (short)f2bf(v1.x); t[5] = (short)f2bf(v1.y);
            t[6] = (short)f2bf(v1.z); t[7] = (short)f2bf(v1.w);
            af[k0] = t;
        } else {
            const unsigned short* Ab = (const unsigned short*)Av;
            af[k0] = *(const short8*)(Ab + (size_t)row * 64 + koff);
        }
    }

    __syncthreads();                          // LDS B ready

#pragma unroll
    for (int cb = 0; cb < NSLAB; ++cb) {
        int col0 = cb * 64;
        floatx4 acc[4] = {};
#pragma unroll
        for (int k0 = 0; k0 < 2; ++k0) {
#pragma unroll
            for (int g = 0; g < 4; ++g) {
                short8 b = *(const short8*)(Bs + ((cb * 2 + k0) * 4 + g) * 512 + lane * 8);
                acc[g] = __builtin_amdgcn_mfma_f32_16x16x32_bf16(b, af[k0], acc[g], 0, 0, 0);
            }
        }
        // thread holds row=rowbase+lr, logical cols col0 + g*16 + lg*4 + i
        if constexpr (AF32) {
            // sigma-phys: within-slab phys col = lg*16 + g*4 + i -> 16 contiguous
            short8 o0, o1;
#pragma unroll
            for (int g = 0; g < 2; ++g)
#pragma unroll
                for (int i = 0; i < 4; ++i) {
                    o0[g * 4 + i] = (short)f2bf(acc[g][i]);
                    o1[g * 4 + i] = (short)f2bf(acc[g + 2][i]);
                }
            unsigned short* p = xw + (size_t)row * NC + col0 + lg * 16;
            *(short8*)p = o0;
            *(short8*)(p + 8) = o1;
        } else {
#pragma unroll
            for (int g = 0; g < 4; ++g) {
                unsigned lo = ((unsigned)f2bf(acc[g][1]) << 16) | f2bf(acc[g][0]);
                unsigned hi = ((unsigned)f2bf(acc[g][3]) << 16) | f2bf(acc[g][2]);
                uint2 o = {lo, hi};
                *(uint2*)(xw + (size_t)row * NC + col0 + g * 16 + lg * 4) = o;
            }
        }
    }
}

// ---- gather-sum + relu -> h bf16 [MP][64] (phys layout); zero pad rows ----
__global__ __launch_bounds__(256) void k_gs_relu(
    const unsigned short* __restrict__ xw,   // [(n*8+r)][64] phys
    const int* __restrict__ ptr, const int* __restrict__ idx,
    const int* __restrict__ rel,
    unsigned short* __restrict__ H, int M, int MP) {
    int rowA = (blockIdx.x * 4 + (threadIdx.x >> 6)) * 2;
    if (rowA >= MP) return;
    rowA = __builtin_amdgcn_readfirstlane(rowA);
    int lane = threadIdx.x & 63;
    int fl = lane & 31, eo = lane >> 5;
    int rowB = rowA + 1;
    int myrow = eo ? rowB : rowA;
    if (rowA >= M) {                          // pad pair -> zeros
        *(unsigned*)(H + (size_t)myrow * 64 + fl * 2) = 0;
        return;
    }
    float cx = 0.f, cy = 0.f;
    bool both = (rowB < M);
    int p0 = ptr[rowA], p1 = ptr[rowA + 1];
    int p2 = both ? ptr[rowA + 2] : p1;
    if (both && (p1 - p0 == 16) && (p2 - p1 == 16)) {
        const int* ia = idx + p0; const int* ra_ = rel + p0;   // scalar (uniform)
        const int* ib = idx + p1; const int* rb_ = rel + p1;
        unsigned u[16];
#pragma unroll
        for (int t = 0; t < 16; ++t) {
            unsigned bA = ((unsigned)ia[t] * 8u + (unsigned)ra_[t]) * 128u;
            unsigned bB = ((unsigned)ib[t] * 8u + (unsigned)rb_[t]) * 128u;
            unsigned b = eo ? bB : bA;
            u[t] = *(const unsigned*)((const char*)xw + b + fl * 4);
        }
#pragma unroll
        for (int t = 0; t < 16; ++t) { cx += bflo(u[t]); cy += bfhi(u[t]); }
    } else {
        int ps = 0, deg = 0;
        if (myrow < M) { ps = ptr[myrow]; deg = ptr[myrow + 1] - ps; }
        for (int t = 0; t < deg; ++t) {
            unsigned b = ((unsigned)idx[ps + t] * 8u + (unsigned)rel[ps + t]) * 128u;
            unsigned u = *(const unsigned*)((const char*)xw + b + fl * 4);
            cx += bflo(u); cy += bfhi(u);
        }
    }
    unsigned o = ((unsigned)f2bf(fmaxf(cy, 0.f)) << 16) | f2bf(fmaxf(cx, 0.f));
    *(unsigned*)(H + (size_t)myrow * 64 + fl * 2) = o;
}

// ---- gather-sum + log_softmax -> out f32 [M][40]  (xw2 logical layout) ----
__global__ __launch_bounds__(256) void k_gs_lsm(
    const unsigned short* __restrict__ xw,   // [(n*8+r)][40] logical
    const int* __restrict__ ptr, const int* __restrict__ idx,
    const int* __restrict__ rel,
    float* __restrict__ out, int M) {
    int rowA = (blockIdx.x * 4 + (threadIdx.x >> 6)) * 2;
    if (rowA >= M) return;
    rowA = __builtin_amdgcn_readfirstlane(rowA);
    int lane = threadIdx.x & 63;
    int fl = lane & 31, eo = lane >> 5;
    int rowB = rowA + 1;
    int myrow = eo ? rowB : rowA;
    bool okf = fl < 20;
    int flc = okf ? fl : 0;
    float cx = 0.f, cy = 0.f;
    bool both = (rowB < M);
    int p0 = ptr[rowA], p1 = ptr[rowA + 1];
    int p2 = both ? ptr[rowA + 2] : p1;
    if (both && (p1 - p0 == 16) && (p2 - p1 == 16)) {
        const int* ia = idx + p0; const int* ra_ = rel + p0;
        const int* ib = idx + p1; const int* rb_ = rel + p1;
        unsigned u[16];
#pragma unroll
        for (int t = 0; t < 16; ++t) {
            unsigned bA = ((unsigned)ia[t] * 8u + (unsigned)ra_[t]) * 80u;
            unsigned bB = ((unsigned)ib[t] * 8u + (unsigned)rb_[t]) * 80u;
            unsigned b = eo ? bB : bA;
            u[t] = *(const unsigned*)((const char*)xw + b + flc * 4);
        }
#pragma unroll
        for (int t = 0; t < 16; ++t) { cx += bflo(u[t]); cy += bfhi(u[t]); }
    } else {
        int ps = 0, deg = 0;
        if (myrow < M) { ps = ptr[myrow]; deg = ptr[myrow + 1] - ps; }
        for (int t = 0; t < deg; ++t) {
            unsigned b = ((unsigned)idx[ps + t] * 8u + (unsigned)rel[ps + t]) * 80u;
            unsigned u = *(const unsigned*)((const char*)xw + b + flc * 4);
            cx += bflo(u); cy += bfhi(u);
        }
    }
    float mx = okf ? fmaxf(cx, cy) : -INFINITY;
#pragma unroll
    for (int m = 1; m < 32; m <<= 1) mx = fmaxf(mx, __shfl_xor(mx, m, 32));
    float s = okf ? (__expf(cx - mx) + __expf(cy - mx)) : 0.f;
#pragma unroll
    for (int m = 1; m < 32; m <<= 1) s += __shfl_xor(s, m, 32);
    float lse = mx + __logf(s);
    if (okf && myrow < M) {
        float2 o = {cx - lse, cy - lse};
        *(float2*)(out + (size_t)myrow * 40 + flc * 2) = o;
    }
}

extern "C" void kernel_launch(void* const* d_in, const int* in_sizes, int n_in,
                              void* d_out, int out_size, void* d_ws, size_t ws_size,
                              hipStream_t stream) {
    const float* x  = (const float*)d_in[0];
    const int* ptr  = (const int*)d_in[1];
    const int* idx  = (const int*)d_in[2];
    const int* rel  = (const int*)d_in[3];
    const float* W1 = (const float*)d_in[4];
    const float* W2 = (const float*)d_in[5];
    float* out = (float*)d_out;

    int N = in_sizes[1] - 1;                 // 75000
    int MP = (N + 255) & ~255;               // 75008

    char* ws = (char*)d_ws;
    size_t szRow64 = (size_t)MP * 64 * 2;    // 9.6MB
    unsigned short* hbf  = (unsigned short*)ws;
    unsigned short* BTf1 = (unsigned short*)(ws + szRow64);
    unsigned short* BTf2 = BTf1 + 32768;
    unsigned short* xwb  = BTf2 + 20480;
    // xw1 [MP][512] = 76.8MB; xw2 [MP][320] aliases it.  Total ws ~= 86.5MB.

    k_packw<<<(32768 + 20480 + 255) / 256, 256, 0, stream>>>(W1, W2, BTf1, BTf2);

    int nblk = MP / 64;                      // 1172 blocks: 4 waves x 16 rows
    // layer 1: xw1 = cast(x) @ W1 (8 slabs, sigma-phys cols, B in 64KB LDS)
    k_xw<1, 8><<<nblk, 256, 0, stream>>>((const void*)x, BTf1, xwb, N);
    k_gs_relu<<<MP / 8, 256, 0, stream>>>(xwb, ptr, idx, rel, hbf, N, MP);
    // layer 2: xw2 = h @ W2 (5 slabs, logical cols, B in 40KB LDS), aliases xwb
    k_xw<0, 5><<<nblk, 256, 0, stream>>>((const void*)hbf, BTf2, xwb, MP);
    k_gs_lsm<<<(N + 7) / 8, 256, 0, stream>>>(xwb, ptr, idx, rel, out, N);
}